// Round 2
// baseline (521.690 us; speedup 1.0000x reference)
//
#include <hip/hip_runtime.h>
#include <cstdint>
#include <cstddef>

#define H      640
#define RH     256
#define NE     5
#define NA     40          // NE * rank
#define NTOK   32768
#define SCAL   2.0f        // alpha/rank = 16/8
#define BK     16
#define BM     128

__device__ __forceinline__ float4 ld4(const float* p) {
    return *reinterpret_cast<const float4*>(p);
}

// ---------------------------------------------------------------------------
// Kernel 1: router (x@W1 -> silu -> @W2 -> softmax -> top2) + low = x@A.
// BM=128 tokens/block, BN=256 (full router hidden), BK=16, 256 threads.
// tm=tid>>4 (16 groups), tn=tid&15. Thread tile: 8 tokens (t=tm+16i) x 16
// cols ((tn+16q)*4+i4). x is read straight from global (broadcast across the
// 16 tn lanes, L1-served) -- no LDS transpose staging. W1 tile in LDS.
// The low-GEMM (x@A, 40 cols) rides on the same register a-values: lanes
// tn<10 own cols tn*4..tn*4+3 (+1 ds_read_b128 per kk).
// ---------------------------------------------------------------------------
__global__ __launch_bounds__(256, 2)
void k_router(const float* __restrict__ x, const float* __restrict__ W1,
              const float* __restrict__ b1v, const float* __restrict__ W2,
              const float* __restrict__ b2v, const float* __restrict__ A,
              float* __restrict__ route_c, int* __restrict__ route_idx)
{
    __shared__ float ws[BK][RH];        // 16 KB
    __shared__ float as_[BK][64];       // 4 KB (rows padded 40->64, cols>=40 garbage)
    __shared__ float w2s[RH * NE];      // 5 KB
    __shared__ float b1s[RH];           // 1 KB
    __shared__ float low_lds[BM][NA];   // 20 KB
    __shared__ float logit_lds[BM][5];  // 2.5 KB

    const int tid  = threadIdx.x;
    const int row0 = blockIdx.x * BM;
    const int tm   = tid >> 4;
    const int tn   = tid & 15;

    for (int i = tid; i < RH * NE; i += 256) w2s[i] = W2[i];
    for (int i = tid; i < RH; i += 256) b1s[i] = b1v[i];

    const float* xrow[8];
    #pragma unroll
    for (int i = 0; i < 8; i++) xrow[i] = x + (size_t)(row0 + tm + 16 * i) * H;

    float acc[8][16];
    #pragma unroll
    for (int i = 0; i < 8; i++)
        #pragma unroll
        for (int j = 0; j < 16; j++) acc[i][j] = 0.f;
    float accl[8][4];
    #pragma unroll
    for (int i = 0; i < 8; i++)
        #pragma unroll
        for (int c = 0; c < 4; c++) accl[i][c] = 0.f;

    for (int k0 = 0; k0 < H; k0 += BK) {
        __syncthreads();
        // stage W1 tile [BK][256] (linear, conflict-free)
        #pragma unroll
        for (int i = 0; i < 4; i++) {
            int idx4 = tid + i * 256;
            int row = idx4 >> 6, c4 = idx4 & 63;
            *reinterpret_cast<float4*>(&ws[row][c4 * 4]) =
                ld4(W1 + (size_t)(k0 + row) * RH + c4 * 4);
        }
        // stage A tile: as_[k][e*8+r] = A[e][k0+k][r]
        if (tid < 160) {
            int row = tid / 10, cc4 = tid % 10;
            int e = cc4 >> 1, r0 = (cc4 & 1) * 4;
            *reinterpret_cast<float4*>(&as_[row][cc4 * 4]) =
                ld4(A + ((size_t)e * H + k0 + row) * 8 + r0);
        }
        __syncthreads();

        #pragma unroll
        for (int kk4 = 0; kk4 < BK; kk4 += 4) {
            float4 a4[8];
            #pragma unroll
            for (int i = 0; i < 8; i++) a4[i] = ld4(xrow[i] + k0 + kk4);
            #pragma unroll
            for (int u = 0; u < 4; u++) {
                float bb[16];
                #pragma unroll
                for (int q = 0; q < 4; q++)
                    *reinterpret_cast<float4*>(&bb[q * 4]) =
                        *reinterpret_cast<const float4*>(&ws[kk4 + u][(tn + 16 * q) * 4]);
                float lb[4];
                *reinterpret_cast<float4*>(lb) =
                    *reinterpret_cast<const float4*>(&as_[kk4 + u][tn * 4]);
                #pragma unroll
                for (int i = 0; i < 8; i++) {
                    float av = (u == 0) ? a4[i].x : (u == 1) ? a4[i].y
                             : (u == 2) ? a4[i].z : a4[i].w;
                    #pragma unroll
                    for (int j = 0; j < 16; j++)
                        acc[i][j] = fmaf(av, bb[j], acc[i][j]);
                    #pragma unroll
                    for (int c = 0; c < 4; c++)
                        accl[i][c] = fmaf(av, lb[c], accl[i][c]);
                }
            }
        }
    }

    // publish low values (only lanes owning real cols)
    if (tn < 10) {
        #pragma unroll
        for (int i = 0; i < 8; i++)
            *reinterpret_cast<float4*>(&low_lds[tm + 16 * i][tn * 4]) =
                *reinterpret_cast<float4*>(&accl[i][0]);
    }

    // silu + b1, partial logits over this thread's 16 cols
    float part[8][5];
    #pragma unroll
    for (int m = 0; m < 8; m++)
        #pragma unroll
        for (int e = 0; e < 5; e++) part[m][e] = 0.f;

    #pragma unroll
    for (int q = 0; q < 4; q++)
        #pragma unroll
        for (int i4 = 0; i4 < 4; i4++) {
            int col = (tn + 16 * q) * 4 + i4;
            float bbias = b1s[col];
            float w2r[5];
            #pragma unroll
            for (int e = 0; e < 5; e++) w2r[e] = w2s[col * 5 + e];
            #pragma unroll
            for (int m = 0; m < 8; m++) {
                float v = acc[m][q * 4 + i4] + bbias;
                float s = __fdividef(v, 1.f + __expf(-v));   // silu
                #pragma unroll
                for (int e = 0; e < 5; e++) part[m][e] = fmaf(s, w2r[e], part[m][e]);
            }
        }

    // reduce partial logits across the 16 tn-lanes
    #pragma unroll
    for (int m = 0; m < 8; m++)
        #pragma unroll
        for (int e = 0; e < 5; e++) {
            float v = part[m][e];
            v += __shfl_xor(v, 1);
            v += __shfl_xor(v, 2);
            v += __shfl_xor(v, 4);
            v += __shfl_xor(v, 8);
            part[m][e] = v;
        }

    if (tn == 0) {
        #pragma unroll
        for (int m = 0; m < 8; m++)
            #pragma unroll
            for (int e = 0; e < 5; e++) logit_lds[tm + 16 * m][e] = part[m][e];
    }
    __syncthreads();

    // one thread per token: top-2 + route_c write
    if (tid < BM) {
        const int t = tid;
        float l0 = logit_lds[t][0] + b2v[0];
        float l1 = logit_lds[t][1] + b2v[1];
        float l2 = logit_lds[t][2] + b2v[2];
        float l3 = logit_lds[t][3] + b2v[3];
        float l4 = logit_lds[t][4] + b2v[4];
        int   i0 = 0;  float m0 = l0;
        int   i1 = -1; float m1 = -3.4e38f;
        if (l1 > m0) { m1 = m0; i1 = i0; m0 = l1; i0 = 1; } else if (l1 > m1) { m1 = l1; i1 = 1; }
        if (l2 > m0) { m1 = m0; i1 = i0; m0 = l2; i0 = 2; } else if (l2 > m1) { m1 = l2; i1 = 2; }
        if (l3 > m0) { m1 = m0; i1 = i0; m0 = l3; i0 = 3; } else if (l3 > m1) { m1 = l3; i1 = 3; }
        if (l4 > m0) { m1 = m0; i1 = i0; m0 = l4; i0 = 4; } else if (l4 > m1) { m1 = l4; i1 = 4; }
        float w1r = __expf(m1 - m0);
        float inv = __fdividef(1.f, 1.f + w1r);
        float c0 = inv * SCAL;
        float c1 = w1r * inv * SCAL;
        int gt = row0 + t;
        #pragma unroll
        for (int r4 = 0; r4 < 2; r4++) {
            float4 v0 = ld4(&low_lds[t][i0 * 8 + r4 * 4]);
            v0.x *= c0; v0.y *= c0; v0.z *= c0; v0.w *= c0;
            *reinterpret_cast<float4*>(&route_c[(size_t)gt * 16 + r4 * 4]) = v0;
            float4 v1 = ld4(&low_lds[t][i1 * 8 + r4 * 4]);
            v1.x *= c1; v1.y *= c1; v1.z *= c1; v1.w *= c1;
            *reinterpret_cast<float4*>(&route_c[(size_t)gt * 16 + 8 + r4 * 4]) = v1;
        }
        route_idx[gt * 2 + 0] = i0;
        route_idx[gt * 2 + 1] = i1;
    }
}

// ---------------------------------------------------------------------------
// Kernel 2: out[t] = base[t] + sum_j c[t][j] * Bm_row[idx_j][:]
// All of Bm (40x640 f32 = 102.4 KB) staged in LDS. 512 thr (8 waves), one
// wave per token at a time; grid = 256 blocks * 128 tokens.
// ---------------------------------------------------------------------------
__global__ __launch_bounds__(512)
void k_combine(const float* __restrict__ base, const float* __restrict__ Bm,
               const float* __restrict__ route_c, const int* __restrict__ route_idx,
               float* __restrict__ out)
{
    __shared__ float bs[NA][H];
    const int tid = threadIdx.x;
    for (int i4 = tid; i4 < NA * H / 4; i4 += 512)
        reinterpret_cast<float4*>(&bs[0][0])[i4] = reinterpret_cast<const float4*>(Bm)[i4];
    __syncthreads();

    const int w    = tid >> 6;
    const int lane = tid & 63;

    for (int it = 0; it < 16; it++) {
        int t = blockIdx.x * 128 + w * 16 + it;
        t = __builtin_amdgcn_readfirstlane(t);
        const int e0 = route_idx[t * 2 + 0];
        const int e1 = route_idx[t * 2 + 1];
        float cc[16];
        #pragma unroll
        for (int q = 0; q < 4; q++)
            *reinterpret_cast<float4*>(&cc[q * 4]) = ld4(route_c + (size_t)t * 16 + q * 4);

        const float* brow0 = &bs[e0 * 8][0];
        const float* brow1 = &bs[e1 * 8][0];
        const float* bp = base + (size_t)t * H;
        float*       op = out  + (size_t)t * H;

        #pragma unroll
        for (int i = 0; i < 2; i++) {
            int h = i * 256 + lane * 4;
            float4 a = ld4(bp + h);
            #pragma unroll
            for (int j = 0; j < 8; j++) {
                float4 bv = *reinterpret_cast<const float4*>(brow0 + j * H + h);
                a.x = fmaf(cc[j], bv.x, a.x); a.y = fmaf(cc[j], bv.y, a.y);
                a.z = fmaf(cc[j], bv.z, a.z); a.w = fmaf(cc[j], bv.w, a.w);
            }
            #pragma unroll
            for (int j = 0; j < 8; j++) {
                float4 bv = *reinterpret_cast<const float4*>(brow1 + j * H + h);
                a.x = fmaf(cc[8 + j], bv.x, a.x); a.y = fmaf(cc[8 + j], bv.y, a.y);
                a.z = fmaf(cc[8 + j], bv.z, a.z); a.w = fmaf(cc[8 + j], bv.w, a.w);
            }
            *reinterpret_cast<float4*>(op + h) = a;
        }
        {
            int h = 512 + lane * 2;
            float2 a = *reinterpret_cast<const float2*>(bp + h);
            #pragma unroll
            for (int j = 0; j < 8; j++) {
                float2 bv = *reinterpret_cast<const float2*>(brow0 + j * H + h);
                a.x = fmaf(cc[j], bv.x, a.x); a.y = fmaf(cc[j], bv.y, a.y);
            }
            #pragma unroll
            for (int j = 0; j < 8; j++) {
                float2 bv = *reinterpret_cast<const float2*>(brow1 + j * H + h);
                a.x = fmaf(cc[8 + j], bv.x, a.x); a.y = fmaf(cc[8 + j], bv.y, a.y);
            }
            *reinterpret_cast<float2*>(op + h) = a;
        }
    }
}

extern "C" void kernel_launch(void* const* d_in, const int* in_sizes, int n_in,
                              void* d_out, int out_size, void* d_ws, size_t ws_size,
                              hipStream_t stream)
{
    const float* x  = (const float*)d_in[0];
    const float* bo = (const float*)d_in[1];
    const float* W1 = (const float*)d_in[2];
    const float* b1 = (const float*)d_in[3];
    const float* W2 = (const float*)d_in[4];
    const float* b2 = (const float*)d_in[5];
    const float* A  = (const float*)d_in[6];
    const float* Bm = (const float*)d_in[7];
    float* out = (float*)d_out;

    float* route_c   = (float*)d_ws;                                   // 32768*16 f32 = 2 MB
    int*   route_idx = (int*)((char*)d_ws + (size_t)NTOK * 16 * 4);    // 32768*2 i32 = 256 KB

    k_router<<<dim3(NTOK / BM), dim3(256), 0, stream>>>(
        x, W1, b1, W2, b2, A, route_c, route_idx);
    k_combine<<<dim3(256), dim3(512), 0, stream>>>(
        bo, Bm, route_c, route_idx, out);
}

// Round 3
// 236.593 us; speedup vs baseline: 2.2050x; 2.2050x over previous
//
#include <hip/hip_runtime.h>
#include <cstdint>
#include <cstddef>

#define H      640
#define RH     256
#define NE     5
#define NA     40          // NE * rank
#define NTOK   32768
#define SCAL   2.0f        // alpha/rank = 16/8
#define BK     16
#define BM     32          // tokens per block -> grid 1024 = 4 blocks/CU

__device__ __forceinline__ float4 ld4(const float* p) {
    return *reinterpret_cast<const float4*>(p);
}

// ---------------------------------------------------------------------------
// Kernel 1: router (x@W1 -> silu -> @W2 -> softmax -> top2) + low = x@A.
// BM=32 tokens/block, BN=256 (full router hidden -> fused epilogue), BK=16,
// 256 threads, grid=1024 (4 blocks/CU, ~16 waves/CU for latency hiding).
// tm=tid>>4 (16 groups x 2 tokens), tn=tid&15 (16 col-groups x 16 cols).
// Thread tile: 2 tokens x 16 cols (acc[2][16]) + 2 tokens x 4 low-cols
// (lanes tn<10 own the 40 low cols). x tile in LDS [m][k] (row padded to 20,
// conflict-free f4 stores, b128 per-kk4 reads); W1 tile in LDS (linear).
// 16 tm-lanes read identical ws/as_ addresses -> LDS broadcast (free).
// ---------------------------------------------------------------------------
__global__ __launch_bounds__(256, 4)
void k_router(const float* __restrict__ x, const float* __restrict__ W1,
              const float* __restrict__ b1v, const float* __restrict__ W2,
              const float* __restrict__ b2v, const float* __restrict__ A,
              float* __restrict__ route_c, int* __restrict__ route_idx)
{
    __shared__ float xs[BM][20];        // 2.56 KB  (16 k-cols padded to 20)
    __shared__ float ws[BK][RH];        // 16 KB
    __shared__ float as_[BK][64];       // 4 KB (40 cols padded to 64)
    __shared__ float w2s[RH * NE];      // 5 KB
    __shared__ float b1s[RH];           // 1 KB
    __shared__ float low_lds[BM][NA];   // 5.12 KB
    __shared__ float logit_lds[BM][8];  // 1 KB

    const int tid  = threadIdx.x;
    const int row0 = blockIdx.x * BM;
    const int tm   = tid >> 4;
    const int tn   = tid & 15;

    for (int i = tid; i < RH * NE; i += 256) w2s[i] = W2[i];
    if (tid < RH) b1s[tid] = b1v[tid];

    float acc[2][16];
    #pragma unroll
    for (int j = 0; j < 2; j++)
        #pragma unroll
        for (int c = 0; c < 16; c++) acc[j][c] = 0.f;
    float accl[2][4];
    #pragma unroll
    for (int j = 0; j < 2; j++)
        #pragma unroll
        for (int c = 0; c < 4; c++) accl[j][c] = 0.f;

    for (int k0 = 0; k0 < H; k0 += BK) {
        __syncthreads();
        // stage x tile [32][16] (natural layout, conflict-free)
        if (tid < 128) {
            int m = tid >> 2, c = tid & 3;
            *reinterpret_cast<float4*>(&xs[m][c * 4]) =
                ld4(x + (size_t)(row0 + m) * H + k0 + c * 4);
        }
        // stage W1 tile [BK][256] (linear, conflict-free)
        #pragma unroll
        for (int i = 0; i < 4; i++) {
            int idx4 = tid + i * 256;
            int row = idx4 >> 6, c4 = idx4 & 63;
            *reinterpret_cast<float4*>(&ws[row][c4 * 4]) =
                ld4(W1 + (size_t)(k0 + row) * RH + c4 * 4);
        }
        // stage A tile: as_[k][e*8+r] = A[e][k0+k][r]
        if (tid < 160) {
            int row = tid / 10, c4 = tid % 10;
            int e = c4 >> 1, r0 = (c4 & 1) * 4;
            *reinterpret_cast<float4*>(&as_[row][c4 * 4]) =
                ld4(A + ((size_t)e * H + k0 + row) * 8 + r0);
        }
        __syncthreads();

        #pragma unroll
        for (int kk4 = 0; kk4 < BK; kk4 += 4) {
            float4 xa0 = *reinterpret_cast<const float4*>(&xs[2 * tm + 0][kk4]);
            float4 xa1 = *reinterpret_cast<const float4*>(&xs[2 * tm + 1][kk4]);
            #pragma unroll
            for (int u = 0; u < 4; u++) {
                float bb[16];
                #pragma unroll
                for (int q = 0; q < 4; q++)
                    *reinterpret_cast<float4*>(&bb[q * 4]) =
                        *reinterpret_cast<const float4*>(&ws[kk4 + u][(tn + 16 * q) * 4]);
                float lb[4];
                *reinterpret_cast<float4*>(lb) =
                    *reinterpret_cast<const float4*>(&as_[kk4 + u][tn * 4]);
                float av0 = (u == 0) ? xa0.x : (u == 1) ? xa0.y : (u == 2) ? xa0.z : xa0.w;
                float av1 = (u == 0) ? xa1.x : (u == 1) ? xa1.y : (u == 2) ? xa1.z : xa1.w;
                #pragma unroll
                for (int c = 0; c < 16; c++) {
                    acc[0][c] = fmaf(av0, bb[c], acc[0][c]);
                    acc[1][c] = fmaf(av1, bb[c], acc[1][c]);
                }
                #pragma unroll
                for (int c = 0; c < 4; c++) {
                    accl[0][c] = fmaf(av0, lb[c], accl[0][c]);
                    accl[1][c] = fmaf(av1, lb[c], accl[1][c]);
                }
            }
        }
    }

    // publish low values (lanes owning real cols)
    if (tn < 10) {
        #pragma unroll
        for (int j = 0; j < 2; j++)
            *reinterpret_cast<float4*>(&low_lds[2 * tm + j][tn * 4]) =
                *reinterpret_cast<float4*>(&accl[j][0]);
    }

    // silu + b1, partial logits over this thread's 16 cols
    float part[2][5];
    #pragma unroll
    for (int j = 0; j < 2; j++)
        #pragma unroll
        for (int e = 0; e < 5; e++) part[j][e] = 0.f;

    #pragma unroll
    for (int q = 0; q < 4; q++)
        #pragma unroll
        for (int i4 = 0; i4 < 4; i4++) {
            int col = (tn + 16 * q) * 4 + i4;
            float bbias = b1s[col];
            float w2r[5];
            #pragma unroll
            for (int e = 0; e < 5; e++) w2r[e] = w2s[col * 5 + e];
            #pragma unroll
            for (int j = 0; j < 2; j++) {
                float v = acc[j][q * 4 + i4] + bbias;
                float s = __fdividef(v, 1.f + __expf(-v));   // silu
                #pragma unroll
                for (int e = 0; e < 5; e++) part[j][e] = fmaf(s, w2r[e], part[j][e]);
            }
        }

    // reduce partial logits across the 16 tn-lanes
    #pragma unroll
    for (int j = 0; j < 2; j++)
        #pragma unroll
        for (int e = 0; e < 5; e++) {
            float v = part[j][e];
            v += __shfl_xor(v, 1);
            v += __shfl_xor(v, 2);
            v += __shfl_xor(v, 4);
            v += __shfl_xor(v, 8);
            part[j][e] = v;
        }

    if (tn == 0) {
        #pragma unroll
        for (int j = 0; j < 2; j++)
            #pragma unroll
            for (int e = 0; e < 5; e++) logit_lds[2 * tm + j][e] = part[j][e];
    }
    __syncthreads();

    // one thread per token: top-2 + route_c write
    if (tid < BM) {
        const int t = tid;
        float l0 = logit_lds[t][0] + b2v[0];
        float l1 = logit_lds[t][1] + b2v[1];
        float l2 = logit_lds[t][2] + b2v[2];
        float l3 = logit_lds[t][3] + b2v[3];
        float l4 = logit_lds[t][4] + b2v[4];
        int   i0 = 0;  float m0 = l0;
        int   i1 = -1; float m1 = -3.4e38f;
        if (l1 > m0) { m1 = m0; i1 = i0; m0 = l1; i0 = 1; } else if (l1 > m1) { m1 = l1; i1 = 1; }
        if (l2 > m0) { m1 = m0; i1 = i0; m0 = l2; i0 = 2; } else if (l2 > m1) { m1 = l2; i1 = 2; }
        if (l3 > m0) { m1 = m0; i1 = i0; m0 = l3; i0 = 3; } else if (l3 > m1) { m1 = l3; i1 = 3; }
        if (l4 > m0) { m1 = m0; i1 = i0; m0 = l4; i0 = 4; } else if (l4 > m1) { m1 = l4; i1 = 4; }
        float w1r = __expf(m1 - m0);
        float inv = __fdividef(1.f, 1.f + w1r);
        float c0 = inv * SCAL;
        float c1 = w1r * inv * SCAL;
        int gt = row0 + t;
        #pragma unroll
        for (int r4 = 0; r4 < 2; r4++) {
            float4 v0 = ld4(&low_lds[t][i0 * 8 + r4 * 4]);
            v0.x *= c0; v0.y *= c0; v0.z *= c0; v0.w *= c0;
            *reinterpret_cast<float4*>(&route_c[(size_t)gt * 16 + r4 * 4]) = v0;
            float4 v1 = ld4(&low_lds[t][i1 * 8 + r4 * 4]);
            v1.x *= c1; v1.y *= c1; v1.z *= c1; v1.w *= c1;
            *reinterpret_cast<float4*>(&route_c[(size_t)gt * 16 + 8 + r4 * 4]) = v1;
        }
        route_idx[gt * 2 + 0] = i0;
        route_idx[gt * 2 + 1] = i1;
    }
}

// ---------------------------------------------------------------------------
// Kernel 2: out[t] = base[t] + sum_j c[t][j] * Bm_row[idx_j][:]
// All of Bm (40x640 f32 = 102.4 KB) staged in LDS. 512 thr (8 waves), one
// wave per token at a time; grid = 256 blocks * 128 tokens.
// ---------------------------------------------------------------------------
__global__ __launch_bounds__(512)
void k_combine(const float* __restrict__ base, const float* __restrict__ Bm,
               const float* __restrict__ route_c, const int* __restrict__ route_idx,
               float* __restrict__ out)
{
    __shared__ float bs[NA][H];
    const int tid = threadIdx.x;
    for (int i4 = tid; i4 < NA * H / 4; i4 += 512)
        reinterpret_cast<float4*>(&bs[0][0])[i4] = reinterpret_cast<const float4*>(Bm)[i4];
    __syncthreads();

    const int w    = tid >> 6;
    const int lane = tid & 63;

    for (int it = 0; it < 16; it++) {
        int t = blockIdx.x * 128 + w * 16 + it;
        t = __builtin_amdgcn_readfirstlane(t);
        const int e0 = route_idx[t * 2 + 0];
        const int e1 = route_idx[t * 2 + 1];
        float cc[16];
        #pragma unroll
        for (int q = 0; q < 4; q++)
            *reinterpret_cast<float4*>(&cc[q * 4]) = ld4(route_c + (size_t)t * 16 + q * 4);

        const float* brow0 = &bs[e0 * 8][0];
        const float* brow1 = &bs[e1 * 8][0];
        const float* bp = base + (size_t)t * H;
        float*       op = out  + (size_t)t * H;

        #pragma unroll
        for (int i = 0; i < 2; i++) {
            int h = i * 256 + lane * 4;
            float4 a = ld4(bp + h);
            #pragma unroll
            for (int j = 0; j < 8; j++) {
                float4 bv = *reinterpret_cast<const float4*>(brow0 + j * H + h);
                a.x = fmaf(cc[j], bv.x, a.x); a.y = fmaf(cc[j], bv.y, a.y);
                a.z = fmaf(cc[j], bv.z, a.z); a.w = fmaf(cc[j], bv.w, a.w);
            }
            #pragma unroll
            for (int j = 0; j < 8; j++) {
                float4 bv = *reinterpret_cast<const float4*>(brow1 + j * H + h);
                a.x = fmaf(cc[8 + j], bv.x, a.x); a.y = fmaf(cc[8 + j], bv.y, a.y);
                a.z = fmaf(cc[8 + j], bv.z, a.z); a.w = fmaf(cc[8 + j], bv.w, a.w);
            }
            *reinterpret_cast<float4*>(op + h) = a;
        }
        {
            int h = 512 + lane * 2;
            float2 a = *reinterpret_cast<const float2*>(bp + h);
            #pragma unroll
            for (int j = 0; j < 8; j++) {
                float2 bv = *reinterpret_cast<const float2*>(brow0 + j * H + h);
                a.x = fmaf(cc[j], bv.x, a.x); a.y = fmaf(cc[j], bv.y, a.y);
            }
            #pragma unroll
            for (int j = 0; j < 8; j++) {
                float2 bv = *reinterpret_cast<const float2*>(brow1 + j * H + h);
                a.x = fmaf(cc[8 + j], bv.x, a.x); a.y = fmaf(cc[8 + j], bv.y, a.y);
            }
            *reinterpret_cast<float2*>(op + h) = a;
        }
    }
}

extern "C" void kernel_launch(void* const* d_in, const int* in_sizes, int n_in,
                              void* d_out, int out_size, void* d_ws, size_t ws_size,
                              hipStream_t stream)
{
    const float* x  = (const float*)d_in[0];
    const float* bo = (const float*)d_in[1];
    const float* W1 = (const float*)d_in[2];
    const float* b1 = (const float*)d_in[3];
    const float* W2 = (const float*)d_in[4];
    const float* b2 = (const float*)d_in[5];
    const float* A  = (const float*)d_in[6];
    const float* Bm = (const float*)d_in[7];
    float* out = (float*)d_out;

    float* route_c   = (float*)d_ws;                                   // 32768*16 f32 = 2 MB
    int*   route_idx = (int*)((char*)d_ws + (size_t)NTOK * 16 * 4);    // 32768*2 i32 = 256 KB

    k_router<<<dim3(NTOK / BM), dim3(256), 0, stream>>>(
        x, W1, b1, W2, b2, A, route_c, route_idx);
    k_combine<<<dim3(256), dim3(512), 0, stream>>>(
        bo, Bm, route_c, route_idx, out);
}